// Round 2
// baseline (354.303 us; speedup 1.0000x reference)
//
#include <hip/hip_runtime.h>
#include <math.h>

#define HH 512
#define WW 512
#define NB 64
#define CH_STRIDE (HH*WW)
#define IMG_STRIDE (3*CH_STRIDE)

// 5-tap Gaussian, sigma=1.0 (matches cv2.getGaussianKernel(5,1.0) in f32)
#define GK0 0.0544886846f
#define GK1 0.2442013419f
#define GK2 0.4026199468f

__device__ __forceinline__ float quant255(float v) {
    // floor(clip(v*255, 0, 255)); _rn ops to avoid FMA contraction changing boundaries
    return floorf(fminf(fmaxf(__fmul_rn(v, 255.0f), 0.0f), 255.0f));
}
__device__ __forceinline__ float gray255(float qa, float qb, float qc) {
    // rint = round-half-even, matches jnp.round; stays in x255 domain (no /255)
    return rintf(__fadd_rn(__fadd_rn(__fmul_rn(0.299f, qa), __fmul_rn(0.587f, qb)),
                           __fadd_rn(__fmul_rn(0.114f, qc), 0.0f)));
}

// v3: float2/lane (128-col strips) to halve per-lane register state -> target
// <=128 VGPR -> 4 waves/SIMD (was 2). 4096 waves total. One-row-ahead register
// prefetch kept (incl. strip-edge halo loads). Bijective XCD swizzle so each
// XCD owns 8 whole images. Histogram LDS sub-split widened to lane&3.
__global__ __launch_bounds__(256, 4)
void noise_main(const float* __restrict__ x, float* __restrict__ gsums,
                unsigned int* __restrict__ ghist)
{
    __shared__ unsigned int lhist[4][4][50];
    const int tid  = threadIdx.x;
    const int lane = tid & 63;
    const int wid  = tid >> 6;
    for (int i = tid; i < 800; i += 256) ((unsigned int*)lhist)[i] = 0u;
    __syncthreads();

    // XCD-aware bijective swizzle: 1024 blocks, 8 XCDs -> XCD k gets images 8k..8k+7
    const int rawblk = blockIdx.x;
    const int blk = (rawblk & 7) * 128 + (rawblk >> 3);

    const int b     = blk >> 4;        // image 0..63
    const int strip = (blk >> 2) & 3;  // 0..3 (128-col strips)
    const int cg    = blk & 3;         // chunk group
    const int chunk = cg * 4 + wid;    // 0..15
    const int R0    = chunk * 32;      // first output row
    const int X0    = strip * 128;     // first col of strip
    const int gcol  = X0 + lane * 2;

    const float* pa = x + (size_t)b * IMG_STRIDE;
    const float* pb = pa + CH_STRIDE;
    const float* pc = pb + CH_STRIDE;

    const bool eL  = (lane == 0)  && (X0 != 0);    // needs left-strip halo loads
    const bool eR  = (lane == 63) && (X0 != 384);  // needs right-strip halo loads
    const bool eLR = eL || eR;
    const int  ecol = eL ? (X0 - 2) : (X0 + 128);  // only meaningful when eLR

    // horizontal-blur rings [slot][col], slot = t % 5 (static via unroll 5)
    float hrA[5][2], hrB[5][2], hrC[5][2], hrG[5][2];
    // raw-center delays (row t-1, t-2)
    float d1A[2], d1B[2], d1C[2], d1G[2];
    float d2A[2], d2B[2], d2C[2], d2G[2];
    float sA=0.f,qA=0.f,sB=0.f,qB=0.f,sC=0.f,qC=0.f,sG=0.f,qG=0.f;

    // current row + prefetched next row (main float2 per channel + shared edge float2)
    float2 va = {0,0}, vb = {0,0}, vc = {0,0};
    float2 e_a = {0,0}, e_b = {0,0}, e_c = {0,0};
    float2 nva = {0,0}, nvb = {0,0}, nvc = {0,0};
    float2 ne_a = {0,0}, ne_b = {0,0}, ne_c = {0,0};

#define LOADROW(T, VA_, VB_, VC_, EA_, EB_, EC_) do {                           \
        int r_ = R0 - 2 + (T);                                                  \
        r_ = (r_ < 0) ? -r_ : ((r_ >= HH) ? (2*(HH-1) - r_) : r_);              \
        const int ro_ = r_ * WW;                                                \
        VA_ = *(const float2*)(pa + ro_ + gcol);                                \
        VB_ = *(const float2*)(pb + ro_ + gcol);                                \
        VC_ = *(const float2*)(pc + ro_ + gcol);                                \
        if (eLR) {                                                              \
            EA_ = *(const float2*)(pa + ro_ + ecol);                            \
            EB_ = *(const float2*)(pb + ro_ + ecol);                            \
            EC_ = *(const float2*)(pc + ro_ + ecol);                            \
        }                                                                       \
    } while (0)

    // preload row-step 0
    LOADROW(0, va, vb, vc, e_a, e_b, e_c);

    #pragma unroll 1
    for (int tb = 0; tb < 8; ++tb) {
        #pragma unroll
        for (int u = 0; u < 5; ++u) {
            const int t = tb * 5 + u;          // row step; slot = u
            if (t < 36) {
                // ---- prefetch next row first: the whole body below is its cover ----
                if (t + 1 < 36)
                    LOADROW(t + 1, nva, nvb, nvc, ne_a, ne_b, ne_c);

                // quantized gray (x255 domain), own 2 cols
                float g0 = gray255(quant255(va.x), quant255(vb.x), quant255(vc.x));
                float g1 = gray255(quant255(va.y), quant255(vb.y), quant255(vc.y));

                // horizontal halo via shuffles: raw cols gcol-2,gcol-1 / gcol+2,gcol+3
                float l2a = __shfl_up(va.x, 1), l1a = __shfl_up(va.y, 1);
                float l2b = __shfl_up(vb.x, 1), l1b = __shfl_up(vb.y, 1);
                float l2c = __shfl_up(vc.x, 1), l1c = __shfl_up(vc.y, 1);
                float r0a = __shfl_down(va.x, 1), r1a = __shfl_down(va.y, 1);
                float r0b = __shfl_down(vb.x, 1), r1b = __shfl_down(vb.y, 1);
                float r0c = __shfl_down(vc.x, 1), r1c = __shfl_down(vc.y, 1);
                float gl2 = __shfl_up(g0, 1),   gl1 = __shfl_up(g1, 1);
                float gr0 = __shfl_down(g0, 1), gr1 = __shfl_down(g1, 1);

                if (lane == 0) {
                    if (X0 == 0) { // reflect-101: col -2 -> col 2 (=r0), col -1 -> col 1 (=v.y)
                        l2a = r0a; l1a = va.y; l2b = r0b; l1b = vb.y; l2c = r0c; l1c = vc.y;
                        gl2 = gr0; gl1 = g1;
                    } else {       // cols X0-2,X0-1 from the left strip (prefetched)
                        l2a = e_a.x; l1a = e_a.y; l2b = e_b.x; l1b = e_b.y; l2c = e_c.x; l1c = e_c.y;
                        gl2 = gray255(quant255(e_a.x), quant255(e_b.x), quant255(e_c.x));
                        gl1 = gray255(quant255(e_a.y), quant255(e_b.y), quant255(e_c.y));
                    }
                }
                if (lane == 63) {
                    if (X0 != 384) { // cols X0+128,X0+129 from the right strip (prefetched)
                        r0a = e_a.x; r1a = e_a.y; r0b = e_b.x; r1b = e_b.y; r0c = e_c.x; r1c = e_c.y;
                        gr0 = gray255(quant255(e_a.x), quant255(e_b.x), quant255(e_c.x));
                        gr1 = gray255(quant255(e_a.y), quant255(e_b.y), quant255(e_c.y));
                    } else {         // reflect-101: col 512 -> 510 (=v.x), col 513 -> 509 (=l1)
                        r0a = va.x; r1a = l1a; r0b = vb.x; r1b = l1b; r0c = vc.x; r1c = l1c;
                        gr0 = g0;   gr1 = gl1;
                    }
                }

                // horizontal blur of row t -> ring slot u (2 cols per quantity)
                hrA[u][0] = GK0*(l2a+r0a) + GK1*(l1a+va.y) + GK2*va.x;
                hrA[u][1] = GK0*(l1a+r1a) + GK1*(va.x+r0a) + GK2*va.y;
                hrB[u][0] = GK0*(l2b+r0b) + GK1*(l1b+vb.y) + GK2*vb.x;
                hrB[u][1] = GK0*(l1b+r1b) + GK1*(vb.x+r0b) + GK2*vb.y;
                hrC[u][0] = GK0*(l2c+r0c) + GK1*(l1c+vc.y) + GK2*vc.x;
                hrC[u][1] = GK0*(l1c+r1c) + GK1*(vc.x+r0c) + GK2*vc.y;
                hrG[u][0] = GK0*(gl2+gr0) + GK1*(gl1+g1)  + GK2*g0;
                hrG[u][1] = GK0*(gl1+gr1) + GK1*(g0+gr0)  + GK2*g1;

                // output: center row t-2 (valid for t in [4,35])
                if (t >= 4) {
                    const int s0=(u+1)%5, s1=(u+2)%5, s2=(u+3)%5, s3=(u+4)%5, s4=u;
                    #pragma unroll
                    for (int j = 0; j < 2; ++j) {
                        float bl, v;
                        bl = GK0*(hrA[s0][j]+hrA[s4][j]) + GK1*(hrA[s1][j]+hrA[s3][j]) + GK2*hrA[s2][j];
                        v  = d2A[j] - bl;  sA += v;  qA = fmaf(v, v, qA);
                        bl = GK0*(hrB[s0][j]+hrB[s4][j]) + GK1*(hrB[s1][j]+hrB[s3][j]) + GK2*hrB[s2][j];
                        v  = d2B[j] - bl;  sB += v;  qB = fmaf(v, v, qB);
                        bl = GK0*(hrC[s0][j]+hrC[s4][j]) + GK1*(hrC[s1][j]+hrC[s3][j]) + GK2*hrC[s2][j];
                        v  = d2C[j] - bl;  sC += v;  qC = fmaf(v, v, qC);
                        bl = GK0*(hrG[s0][j]+hrG[s4][j]) + GK1*(hrG[s1][j]+hrG[s3][j]) + GK2*hrG[s2][j];
                        v  = d2G[j] - bl;  sG += v;  qG = fmaf(v, v, qG);
                        // histogram: x255 domain, bins over (-0.5,0.5)*255, right edge inclusive
                        if (v >= -127.5f && v <= 127.5f) {
                            int idx = (int)((v + 127.5f) * 0.19607843137254902f); // 50/255
                            idx = idx > 49 ? 49 : idx;
                            atomicAdd(&lhist[wid][lane & 3][idx], 1u);
                        }
                    }
                }

                // shift raw-center delays
                #pragma unroll
                for (int j = 0; j < 2; ++j) { d2A[j]=d1A[j]; d2B[j]=d1B[j]; d2C[j]=d1C[j]; d2G[j]=d1G[j]; }
                d1A[0]=va.x; d1A[1]=va.y;
                d1B[0]=vb.x; d1B[1]=vb.y;
                d1C[0]=vc.x; d1C[1]=vc.y;
                d1G[0]=g0;   d1G[1]=g1;

                // rotate prefetched row into current (renamed away inside the unroll)
                va = nva; vb = nvb; vc = nvc;
                e_a = ne_a; e_b = ne_b; e_c = ne_c;
            }
        }
    }
#undef LOADROW

    // wave-reduce 8 accumulators -> one global atomic each
    float acc[8] = {sA, qA, sB, qB, sC, qC, sG, qG};
    #pragma unroll
    for (int f = 0; f < 8; ++f) {
        float v = acc[f];
        #pragma unroll
        for (int o = 32; o > 0; o >>= 1) v += __shfl_down(v, o);
        if (lane == 0) atomicAdd(&gsums[b*8 + f], v);
    }
    __syncthreads();
    if (tid < 50) {
        unsigned int h = 0;
        #pragma unroll
        for (int w = 0; w < 4; ++w)
            #pragma unroll
            for (int p = 0; p < 4; ++p) h += lhist[w][p][tid];
        atomicAdd(&ghist[b*50 + tid], h);
    }
}

// One lane per image: stats -> feats[6] -> 6->32->64 ReLU MLP
__global__ __launch_bounds__(64)
void noise_final(const float* __restrict__ gsums, const unsigned int* __restrict__ ghist,
                 const float* __restrict__ W1, const float* __restrict__ b1,
                 const float* __restrict__ W2, const float* __restrict__ b2,
                 float* __restrict__ out)
{
    const int b = threadIdx.x;
    if (b >= NB) return;
    const float invN = 1.0f / (float)(HH*WW);
    float feats[6];
    {   // gray variance/std (undo x255 scaling)
        float s = gsums[b*8 + 6], q = gsums[b*8 + 7];
        float m = s * invN;
        float var255 = q * invN - m*m;
        var255 = var255 < 0.f ? 0.f : var255;
        float var = var255 * (1.0f/65025.0f);
        feats[0] = var; feats[1] = sqrtf(var);
    }
    {   // histogram entropy
        float tot = 0.f;
        for (int i = 0; i < 50; ++i) tot += (float)ghist[b*50 + i];
        float inv = 1.0f / (tot + 1e-10f);
        float e = 0.f;
        for (int i = 0; i < 50; ++i) {
            float p = (float)ghist[b*50 + i] * inv;
            e -= p * log2f(p + 1e-10f);
        }
        feats[2] = e;
    }
    for (int c = 0; c < 3; ++c) {
        float s = gsums[b*8 + 2*c], q = gsums[b*8 + 2*c + 1];
        float m = s * invN;
        float v = q * invN - m*m;
        feats[3+c] = sqrtf(v < 0.f ? 0.f : v);
    }
    float h[32];
    #pragma unroll
    for (int i = 0; i < 32; ++i) {
        float a = b1[i];
        #pragma unroll
        for (int j = 0; j < 6; ++j) a = fmaf(feats[j], W1[i*6 + j], a);
        h[i] = a > 0.f ? a : 0.f;
    }
    for (int k = 0; k < 64; ++k) {
        float a = b2[k];
        #pragma unroll
        for (int j = 0; j < 32; ++j) a = fmaf(h[j], W2[k*32 + j], a);
        out[b*64 + k] = a > 0.f ? a : 0.f;
    }
}

extern "C" void kernel_launch(void* const* d_in, const int* in_sizes, int n_in,
                              void* d_out, int out_size, void* d_ws, size_t ws_size,
                              hipStream_t stream) {
    (void)in_sizes; (void)n_in; (void)out_size; (void)ws_size;
    const float* x  = (const float*)d_in[0];
    const float* W1 = (const float*)d_in[1];
    const float* b1 = (const float*)d_in[2];
    const float* W2 = (const float*)d_in[3];
    const float* b2 = (const float*)d_in[4];
    float* out = (float*)d_out;

    float* gsums = (float*)d_ws;                                   // [64][8]
    unsigned int* ghist = (unsigned int*)((char*)d_ws + NB*8*4);   // [64][50]
    hipMemsetAsync(d_ws, 0, NB*8*4 + NB*50*4, stream);

    hipLaunchKernelGGL(noise_main, dim3(1024), dim3(256), 0, stream, x, gsums, ghist);
    hipLaunchKernelGGL(noise_final, dim3(1), dim3(64), 0, stream,
                       gsums, ghist, W1, b1, W2, b2, out);
}